// Round 2
// baseline (329.971 us; speedup 1.0000x reference)
//
#include <hip/hip_runtime.h>
#include <math.h>

// Problem constants
#define NF 5
#define NB 8
#define NC 64
#define HW 16384
#define NK 320               // NF*NC
#define FSTRIDE (NB*NC*HW)   // elements per frame = 8388608

// ws layout (floats)
#define EN_FLOATS    (NB*NC*8)   // 4096: per (b,c): E0..E3, N0..N3
#define ALPHA_FLOATS (NB*NK)     // 2560

// ---------------- k0: pack origin_w [64][320] -> Wp[c>>3][k=320][8] ----------------
// Wave w of k1 owns channels 8w..8w+7; its W slice is 320 contiguous 8-float
// rows (10 KB) -> wave-uniform addresses -> scalar (s_load) weight reads.
__global__ void k0_wp(const float* __restrict__ W, float* __restrict__ Wp){
    int idx = blockIdx.x*256 + threadIdx.x;
    if (idx < NC*NK){
        int c = idx / NK;
        int k = idx - c*NK;
        Wp[((c>>3)*NK + k)*8 + (c&7)] = W[idx];
    }
}

__device__ __forceinline__ float redsum64(float v){
#pragma unroll
    for (int m = 1; m < 64; m <<= 1) v += __shfl_xor(v, m, 64);
    return v;
}

// ---------------- k1: fused GEMM + E/N, zero-LDS design ----------------
// Block = 512 thr = 8 waves, grid = 512 (b = blk>>6, s0 = (blk&63)*256).
// Wave wv owns channels c0 = 8*wv; lane l owns 4 spatial floats (float4 =
// 16B/lane, the measured-best shape). Hot loop: NO LDS, NO barriers.
// Per k: 1 coalesced float4 X load + 8 scalar weight floats (s_load, uniform)
// + 32 FMAs. unroll 8 -> 8 X loads in flight per wave. All 8 waves read the
// same X rows -> L1 dedup, HBM sees input exactly once.
// Phase B in-register: thread dots its accs vs (x4-xi) at its 4 spatial
// positions, 6-step shfl_xor butterfly per scalar, lane 0 atomics into EN.
// Accs = 8 x float4 = 32 VGPR; total ~75 -> no spill at 128-VGPR cap.
__global__ __launch_bounds__(512, 4) void k1_fused(
    const float* __restrict__ inp, const float* __restrict__ Wp,
    const float* __restrict__ bias, float* __restrict__ EN)
{
    const int tid = threadIdx.x;
    const int l   = tid & 63;                                   // lane
    const int wv  = __builtin_amdgcn_readfirstlane(tid >> 6);   // wave 0..7 (uniform)
    const int c0  = wv << 3;                                    // 8 channels / wave
    const int b   = blockIdx.x >> 6;
    const int s0  = (blockIdx.x & 63) << 8;                     // 256-float window

    // ---- accumulators, bias-initialized ----
    float4 a0,a1,a2,a3,a4,a5,a6,a7;
    {
        float4 b0 = *reinterpret_cast<const float4*>(bias + c0);
        float4 b1 = *reinterpret_cast<const float4*>(bias + c0 + 4);
        a0 = make_float4(b0.x,b0.x,b0.x,b0.x);
        a1 = make_float4(b0.y,b0.y,b0.y,b0.y);
        a2 = make_float4(b0.z,b0.z,b0.z,b0.z);
        a3 = make_float4(b0.w,b0.w,b0.w,b0.w);
        a4 = make_float4(b1.x,b1.x,b1.x,b1.x);
        a5 = make_float4(b1.y,b1.y,b1.y,b1.y);
        a6 = make_float4(b1.z,b1.z,b1.z,b1.z);
        a7 = make_float4(b1.w,b1.w,b1.w,b1.w);
    }

    const float* wbase = Wp + (size_t)wv * (NK*8);   // this wave's 10 KB W slice

#define FMA4(A, WS) \
    A.x = fmaf(WS, xv.x, A.x); A.y = fmaf(WS, xv.y, A.y); \
    A.z = fmaf(WS, xv.z, A.z); A.w = fmaf(WS, xv.w, A.w);

#pragma unroll 1
    for (int f=0; f<NF; ++f){
        const float* xp = inp + (size_t)(f*NB + b)*NC*HW + s0 + (l << 2);
        const float* wf = wbase + f*64*8;
#pragma unroll 8
        for (int k=0; k<64; ++k){
            float4 xv = *reinterpret_cast<const float4*>(xp);
            xp += HW;
            const float* wk = wf + (k << 3);          // uniform -> s_load x8
            float4 w0 = *reinterpret_cast<const float4*>(wk);
            float4 w1 = *reinterpret_cast<const float4*>(wk + 4);
            FMA4(a0, w0.x) FMA4(a1, w0.y) FMA4(a2, w0.z) FMA4(a3, w0.w)
            FMA4(a4, w1.x) FMA4(a5, w1.y) FMA4(a6, w1.z) FMA4(a7, w1.w)
        }
    }
#undef FMA4

    // ---- Phase B: in-register E/N for this wave's 8 channels ----
    // E[b,c,i] = sum_s o[c,s]*(x4[c,s]-xi[c,s]);  N[b,c,i] = sum_s (x4-xi)^2
#define PHASEB(CC, ACC) { \
    const float* cb = inp + ((size_t)b*NC + (c0+(CC)))*HW + s0 + (l << 2); \
    float4 x4 = *reinterpret_cast<const float4*>(cb + (size_t)4*FSTRIDE); \
    float ev[4], nv[4]; \
    _Pragma("unroll") \
    for (int i=0; i<4; ++i){ \
        float4 xi = *reinterpret_cast<const float4*>(cb + (size_t)i*FSTRIDE); \
        float dx = x4.x - xi.x, dy = x4.y - xi.y; \
        float dz = x4.z - xi.z, dw = x4.w - xi.w; \
        nv[i] = fmaf(dx,dx, fmaf(dy,dy, fmaf(dz,dz, dw*dw))); \
        ev[i] = fmaf((ACC).x,dx, fmaf((ACC).y,dy, fmaf((ACC).z,dz, (ACC).w*dw))); \
    } \
    _Pragma("unroll") \
    for (int i=0; i<4; ++i){ ev[i] = redsum64(ev[i]); nv[i] = redsum64(nv[i]); } \
    if (l == 0){ \
        float* p = EN + ((size_t)b*NC + c0 + (CC))*8; \
        atomicAdd(p+0, ev[0]); atomicAdd(p+1, ev[1]); \
        atomicAdd(p+2, ev[2]); atomicAdd(p+3, ev[3]); \
        atomicAdd(p+4, nv[0]); atomicAdd(p+5, nv[1]); \
        atomicAdd(p+6, nv[2]); atomicAdd(p+7, nv[3]); \
    } }

    PHASEB(0, a0) PHASEB(1, a1) PHASEB(2, a2) PHASEB(3, a3)
    PHASEB(4, a4) PHASEB(5, a5) PHASEB(6, a6) PHASEB(7, a7)
#undef PHASEB
}

// ---------------- k2: finalize coef -> alpha ----------------
__global__ void k2_coef(const float* __restrict__ EN, const float* __restrict__ out_w,
                        float* __restrict__ alpha)
{
    int tid = threadIdx.x;          // 512 = NB*NC
    int b = tid >> 6, c = tid & 63;
    const float* e = EN + (b*NC + c)*8;
    float w1 = out_w[c], w2 = out_w[NC + c];
    float csum = 0.f;
#pragma unroll
    for (int i=0; i<4; ++i){
        float nc = fmaxf(sqrtf(e[4+i]), 1e-12f);
        float coef = e[i] / (nc*nc);
        alpha[b*NK + i*NC + c] = -w1*coef;
        csum += coef;
    }
    alpha[b*NK + 4*NC + c] = w1*csum + w2;
}

// ---------------- k3: y[b,s] = sum_r alpha[b,r]*inp[r,b,s] + out_b ----------------
// v3: 512 blocks x 512 thr (2 blocks/CU, 16 waves/CU). Wave rg (uniform via
// readfirstlane) owns 40 of the 320 rows; alpha read with wave-uniform
// addresses -> s_load, no LDS staging. unroll 8 -> 8 coalesced 1KB row-chunk
// loads in flight. One LDS tree (8 KB) reduces the 8-way row split, then a
// direct float4 store -- no atomics, no y memset.
__global__ __launch_bounds__(512, 4) void k3_out(const float* __restrict__ inp,
        const float* __restrict__ alpha, const float* __restrict__ out_b,
        float* __restrict__ y)
{
    __shared__ float4 P[512];
    const int tid = threadIdx.x;
    const int b   = blockIdx.x >> 6;
    const int s0  = (blockIdx.x & 63) << 8;                     // 256-float window
    const int sg  = tid & 63;
    const int rg  = __builtin_amdgcn_readfirstlane(tid >> 6);   // 0..7: 40-row group

    float4 acc = make_float4(0.f, 0.f, 0.f, 0.f);
    const float* abase = alpha + b*NK + rg*40;
#pragma unroll 8
    for (int j=0; j<40; ++j){
        int r = rg*40 + j;                                      // uniform per wave
        const float* p = inp + (size_t)(((r>>6)*NB + b)*NC + (r&63))*HW + s0 + (sg<<2);
        float  w  = abase[j];                                   // s_load
        float4 xv = *reinterpret_cast<const float4*>(p);
        acc.x = fmaf(w, xv.x, acc.x); acc.y = fmaf(w, xv.y, acc.y);
        acc.z = fmaf(w, xv.z, acc.z); acc.w = fmaf(w, xv.w, acc.w);
    }
    P[tid] = acc;
    __syncthreads();
    if (tid < 64){
        float4 r0 = P[tid];
        float vx = r0.x, vy = r0.y, vz = r0.z, vw = r0.w;
#pragma unroll
        for (int g=1; g<8; ++g){
            float4 q = P[tid + (g<<6)];
            vx += q.x; vy += q.y; vz += q.z; vw += q.w;
        }
        float bb = out_b[0];
        float4 o = make_float4(vx+bb, vy+bb, vz+bb, vw+bb);
        *reinterpret_cast<float4*>(y + (size_t)b*HW + s0 + (tid<<2)) = o;
    }
}

extern "C" void kernel_launch(void* const* d_in, const int* in_sizes, int n_in,
                              void* d_out, int out_size, void* d_ws, size_t ws_size,
                              hipStream_t stream)
{
    const float* inp      = (const float*)d_in[0];
    const float* origin_w = (const float*)d_in[1];
    const float* origin_b = (const float*)d_in[2];
    const float* out_w    = (const float*)d_in[3];
    const float* out_b    = (const float*)d_in[4];
    float* y  = (float*)d_out;
    float* ws = (float*)d_ws;

    float* EN    = ws;                              // 4096 floats
    float* alpha = ws + EN_FLOATS;                  // 2560 floats
    float* Wp    = ws + EN_FLOATS + ALPHA_FLOATS;   // 20480 floats

    hipMemsetAsync(EN, 0, EN_FLOATS*sizeof(float), stream);
    k0_wp   <<<(NC*NK + 255)/256, 256, 0, stream>>>(origin_w, Wp);
    k1_fused<<<512, 512, 0, stream>>>(inp, Wp, origin_b, EN);
    k2_coef <<<1, NB*NC, 0, stream>>>(EN, out_w, alpha);
    k3_out  <<<512, 512, 0, stream>>>(inp, alpha, out_b, y);
}